// Round 7
// baseline (536.626 us; speedup 1.0000x reference)
//
#include <hip/hip_runtime.h>
#include <hip/hip_bf16.h>

// SpatialWindowSelfAttention — MI355X gfx950.
// v7: occupancy via WORKLOAD split (R5/R6 lesson: phase re-ordering cannot push
// the 2-head+outproj wave under 170 VGPR; shrink the wave's job instead).
//   K1 swin_attn: grid 4096 = (window, half). 4 waves, ONE head per wave
//     (attn_head_v6 verbatim). No out-proj. y-half exchanged via uni and
//     stored coalesced (bf16) into ws. hi twin (256,3) + spill guard -> lo.
//   K2 proj_ws: zero-LDS bf16 GEMM out = yb @ wp^T + b (frag-order weights),
//     ~110 VGPR, no LDS -> high occupancy, BW-bound (~201 MB).
// Fallback path (ws too small): original verified two-kernel version.

typedef __bf16 bf16;
typedef bf16 bf16x2 __attribute__((ext_vector_type(2)));
typedef bf16 bf16x4 __attribute__((ext_vector_type(4)));
typedef bf16 bf16x8 __attribute__((ext_vector_type(8)));
typedef float f32x4 __attribute__((ext_vector_type(4)));
typedef int i32x4 __attribute__((ext_vector_type(4)));

#define MFMA16(a, b, c) __builtin_amdgcn_mfma_f32_16x16x32_bf16(a, b, c, 0, 0, 0)

__device__ __forceinline__ bf16x8 cvt8(const float* p) {  // 32B-aligned f32 -> bf16x8
  f32x4 lo = *(const f32x4*)p;
  f32x4 hi = *(const f32x4*)(p + 4);
  bf16x8 r;
#pragma unroll
  for (int j = 0; j < 4; j++) { r[j] = (bf16)lo[j]; r[j + 4] = (bf16)hi[j]; }
  return r;
}
__device__ __forceinline__ bf16x8 lds8(const bf16* p) {  // 8B-aligned LDS pair
  bf16x4 lo = *(const bf16x4*)p;
  bf16x4 hi = *(const bf16x4*)(p + 4);
  return __builtin_shufflevector(lo, hi, 0, 1, 2, 3, 4, 5, 6, 7);
}
__device__ __forceinline__ int pack2(float a, float b) {  // 2 f32 -> bf16x2 dword
  bf16x2 t; t[0] = (bf16)a; t[1] = (bf16)b;
  return __builtin_bit_cast(int, t);
}

// C-layout -> A/B-frag transform (verified v3/v4/v6).
__device__ __forceinline__ bf16x8 frag_xpose(int aLo, int bLo, int aHi, int bHi,
                                             int L0, int L1, bool hiq) {
  const int a0 = __shfl(aLo, L0, 64), a1 = __shfl(aHi, L0, 64);
  const int b0 = __shfl(bLo, L0, 64), b1 = __shfl(bHi, L0, 64);
  const int a0h = __shfl(aLo, L1, 64), a1h = __shfl(aHi, L1, 64);
  const int b0h = __shfl(bLo, L1, 64), b1h = __shfl(bHi, L1, 64);
  const i32x4 w = {hiq ? a1 : a0, hiq ? b1 : b0, hiq ? a1h : a0h, hiq ? b1h : b0h};
  return __builtin_bit_cast(bf16x8, w);
}

// ======================= FAST PATH (v7) =======================

// K0: permute+convert weights into MFMA-fragment order (unchanged, verified).
__global__ __launch_bounds__(256) void cvt_weights_v3(
    const float* __restrict__ wq, const float* __restrict__ wp, bf16* __restrict__ dst) {
  const int did = blockIdx.x * 256 + threadIdx.x;  // [0, 32768)
  const float* src;
  bf16* o;
  if (did < 24576) {
    const int ct = did >> 9, rem = did & 511, kb = rem >> 6, ln = rem & 63;
    src = wq + (size_t)(ct * 16 + (ln & 15)) * 256 + kb * 32 + (ln >> 4) * 8;
    o = dst + (size_t)did * 8;
  } else {
    const int d2 = did - 24576;
    const int ct = d2 >> 9, rem = d2 & 511, kb = rem >> 6, ln = rem & 63;
    src = wp + (size_t)(ct * 16 + (ln & 15)) * 256 + kb * 32 + (ln >> 4) * 8;
    o = dst + 196608 + (size_t)d2 * 8;
  }
  *(bf16x8*)o = cvt8(src);
}

// One 2-tile projection pass (verified v6).
__device__ __forceinline__ void proj2_frags(
    const int ct0, const int cb0, const int lane, const int lr, const int quad,
    const bf16 (*__restrict__ xs)[264], const bf16* __restrict__ wqf,
    const float* __restrict__ wqkv_b, const int L0, const int L1, const bool hiq,
    bf16x8* __restrict__ fr) {
  f32x4 acc[2][4] = {};
#pragma unroll
  for (int kb = 0; kb < 8; ++kb) {
    bf16x8 b[4];
#pragma unroll
    for (int nj = 0; nj < 4; ++nj) b[nj] = lds8(&xs[nj * 16 + lr][kb * 32 + quad * 8]);
#pragma unroll
    for (int mi = 0; mi < 2; ++mi) {
      const bf16x8 a = *(const bf16x8*)&wqf[(size_t)(((ct0 + mi) * 8 + kb) * 64 + lane) * 8];
#pragma unroll
      for (int nj = 0; nj < 4; ++nj) acc[mi][nj] = MFMA16(a, b[nj], acc[mi][nj]);
    }
  }
#pragma unroll
  for (int mi = 0; mi < 2; ++mi) {
    const f32x4 bb = *(const f32x4*)&wqkv_b[cb0 + mi * 16 + quad * 4];
#pragma unroll
    for (int nj = 0; nj < 4; ++nj)
#pragma unroll
      for (int r = 0; r < 4; ++r) acc[mi][nj][r] += bb[r];
  }
#pragma unroll
  for (int t = 0; t < 4; ++t)
    fr[t] = frag_xpose(pack2(acc[0][t][0], acc[0][t][1]), pack2(acc[0][t][2], acc[0][t][3]),
                       pack2(acc[1][t][0], acc[1][t][1]), pack2(acc[1][t][2], acc[1][t][3]),
                       L0, L1, hiq);
}

// Per-head attention (verified v6). y packed into ob[16]
// (tok = mt*16+quad*4+w2*2+e, ch = ni*16+lr within the head's 32).
__device__ __forceinline__ void attn_head_v6(
    const int h, const int lane, const int lr, const int quad,
    const bf16 (*__restrict__ xs)[264], bf16* __restrict__ U,
    const bf16* __restrict__ wqf, const float* __restrict__ wqkv_b,
    const float* __restrict__ bias_table, int* __restrict__ ob) {
  const f32x4 zero = {0.f, 0.f, 0.f, 0.f};
  const float scale = 0.17677669529663687f;  // 1/sqrt(32)
  const int L0 = ((quad & 1) << 5) | lr, L1 = L0 + 16;
  const bool hiq = quad >= 2;

  bf16x8 qf[4], kf[4];
  proj2_frags(2 * h, h * 32, lane, lr, quad, xs, wqf, wqkv_b, L0, L1, hiq, qf);
  proj2_frags(16 + 2 * h, 256 + h * 32, lane, lr, quad, xs, wqf, wqkv_b, L0, L1, hiq, kf);

  bf16x8 pa[4][2];
#pragma unroll
  for (int qp = 0; qp < 2; ++qp) {
    f32x4 s2[4][2];
#pragma unroll
    for (int kt = 0; kt < 4; ++kt)
#pragma unroll
      for (int j = 0; j < 2; ++j) s2[kt][j] = MFMA16(kf[kt], qf[2 * qp + j], zero);
#pragma unroll
    for (int j = 0; j < 2; ++j) {
      const int qt = 2 * qp + j;
      const int qtok = qt * 16 + lr;
#pragma unroll
      for (int kt = 0; kt < 4; ++kt)
#pragma unroll
        for (int r = 0; r < 4; ++r) {
          const int ktok = kt * 16 + quad * 4 + r;
          const int idx = ((qtok >> 3) - (ktok >> 3) + 7) * 15 + (qtok & 7) - (ktok & 7) + 7;
          s2[kt][j][r] = s2[kt][j][r] * scale + bias_table[idx * 8 + h];
        }
      float mx = -1e30f;
#pragma unroll
      for (int kt = 0; kt < 4; ++kt)
#pragma unroll
        for (int r = 0; r < 4; ++r) mx = fmaxf(mx, s2[kt][j][r]);
      mx = fmaxf(mx, __shfl_xor(mx, 16, 64));
      mx = fmaxf(mx, __shfl_xor(mx, 32, 64));
      float sum = 0.f;
#pragma unroll
      for (int kt = 0; kt < 4; ++kt)
#pragma unroll
        for (int r = 0; r < 4; ++r) {
          const float e = __expf(s2[kt][j][r] - mx);
          s2[kt][j][r] = e;
          sum += e;
        }
      sum += __shfl_xor(sum, 16, 64);
      sum += __shfl_xor(sum, 32, 64);
      const float inv = 1.0f / sum;
#pragma unroll
      for (int kq = 0; kq < 2; ++kq)
        pa[qt][kq] = frag_xpose(
            pack2(s2[2 * kq][j][0] * inv, s2[2 * kq][j][1] * inv),
            pack2(s2[2 * kq][j][2] * inv, s2[2 * kq][j][3] * inv),
            pack2(s2[2 * kq + 1][j][0] * inv, s2[2 * kq + 1][j][1] * inv),
            pack2(s2[2 * kq + 1][j][2] * inv, s2[2 * kq + 1][j][3] * inv),
            L0, L1, hiq);
    }
  }

  // V pass -> Vt LDS (acc freed into LDS)
  {
    f32x4 av[2][4] = {};
    const int ctv = 32 + 2 * h;
#pragma unroll
    for (int kb = 0; kb < 8; ++kb) {
      bf16x8 b[4];
#pragma unroll
      for (int nj = 0; nj < 4; ++nj) b[nj] = lds8(&xs[nj * 16 + lr][kb * 32 + quad * 8]);
#pragma unroll
      for (int mi = 0; mi < 2; ++mi) {
        const bf16x8 a = *(const bf16x8*)&wqf[(size_t)(((ctv + mi) * 8 + kb) * 64 + lane) * 8];
#pragma unroll
        for (int nj = 0; nj < 4; ++nj) av[mi][nj] = MFMA16(a, b[nj], av[mi][nj]);
      }
    }
#pragma unroll
    for (int mi = 0; mi < 2; ++mi) {
      const f32x4 bb = *(const f32x4*)&wqkv_b[512 + h * 32 + mi * 16 + quad * 4];
#pragma unroll
      for (int nj = 0; nj < 4; ++nj)
#pragma unroll
        for (int r = 0; r < 4; ++r)
          U[(mi * 16 + quad * 4 + r) * 72 + nj * 16 + lr] = (bf16)(av[mi][nj][r] + bb[r]);
    }
  }

  // O = P @ V
  f32x4 o[4][2] = {};
#pragma unroll
  for (int kq = 0; kq < 2; ++kq) {
    bf16x8 vb[2];
#pragma unroll
    for (int ni = 0; ni < 2; ++ni) vb[ni] = lds8(&U[(ni * 16 + lr) * 72 + kq * 32 + quad * 8]);
#pragma unroll
    for (int mt = 0; mt < 4; ++mt)
#pragma unroll
      for (int ni = 0; ni < 2; ++ni) o[mt][ni] = MFMA16(pa[mt][kq], vb[ni], o[mt][ni]);
  }
#pragma unroll
  for (int mt = 0; mt < 4; ++mt)
#pragma unroll
    for (int ni = 0; ni < 2; ++ni)
#pragma unroll
      for (int w2 = 0; w2 < 2; ++w2)
        ob[(mt * 2 + ni) * 2 + w2] = pack2(o[mt][ni][2 * w2], o[mt][ni][2 * w2 + 1]);
}

// K1 body: (window, half) -> 4 heads, one per wave -> y-half (bf16) into ws.
__device__ __forceinline__ void swin_attn_body(
    bf16 (*__restrict__ xs)[264], bf16 (*__restrict__ uni)[2304],
    const float* __restrict__ x, const bf16* __restrict__ wqf,
    const float* __restrict__ wqkv_b, const float* __restrict__ bias_table,
    bf16* __restrict__ yb) {
  const int tid = threadIdx.x;
  const int wave = tid >> 6, lane = tid & 63;
  const int lr = lane & 15, quad = lane >> 4;
  const int bid = blockIdx.x;               // [0,4096)
  const int win = bid >> 1, hh = bid & 1;   // window, head-half
  const int batch = win >> 10, wy = (win >> 5) & 31, wx = win & 31;
  const int base = batch * 65536 + wy * 2048 + wx * 8;
  bf16* const U = &uni[wave][0];
  const int h = hh * 4 + wave;

  // stage full x window [64 tok][256 ch] f32 -> bf16
  {
    const int tok = tid >> 2, cg = (tid & 3) * 64;
    const float* xp = x + (size_t)(base + ((tok >> 3) << 8) + (tok & 7)) * 256 + cg;
#pragma unroll
    for (int g = 0; g < 8; ++g) *(bf16x8*)&xs[tok][cg + g * 8] = cvt8(xp + g * 8);
  }
  __syncthreads();  // barrier 1

  int ob[16];
  attn_head_v6(h, lane, lr, quad, (const bf16(*)[264])xs, U, wqf, wqkv_b, bias_table, ob);

  __syncthreads();  // barrier 2: all waves done with xs reads AND uni (Vt) use
  // exchange y-half via uni as yh[64][136] (8704 elems <= 4*2304)
  bf16* const yh = &uni[0][0];
#pragma unroll
  for (int mt = 0; mt < 4; ++mt)
#pragma unroll
    for (int ni = 0; ni < 2; ++ni)
#pragma unroll
      for (int w2 = 0; w2 < 2; ++w2) {
        const bf16x2 t = __builtin_bit_cast(bf16x2, ob[(mt * 2 + ni) * 2 + w2]);
#pragma unroll
        for (int e = 0; e < 2; ++e)
          yh[(mt * 16 + quad * 4 + w2 * 2 + e) * 136 + wave * 32 + ni * 16 + lr] = t[e];
      }
  __syncthreads();  // barrier 3: y-half complete
  // coalesced store: 64 B per thread
  {
    const int tok = tid >> 2, cs = (tid & 3) * 32;
    const size_t grow = (size_t)(base + ((tok >> 3) << 8) + (tok & 7));
#pragma unroll
    for (int g = 0; g < 4; ++g)
      *(bf16x8*)&yb[grow * 256 + hh * 128 + cs + g * 8] =
          *(const bf16x8*)&yh[tok * 136 + cs + g * 8];
  }
}

__global__ __launch_bounds__(256, 3) void swin_attn_hi(
    const float* __restrict__ x, const bf16* __restrict__ wqf,
    const float* __restrict__ wqkv_b, const float* __restrict__ bias_table,
    bf16* __restrict__ yb) {
  __shared__ __align__(16) bf16 xs[64][264];
  __shared__ __align__(16) bf16 uni[4][2304];
  swin_attn_body(xs, uni, x, wqf, wqkv_b, bias_table, yb);
}

__global__ __launch_bounds__(256) void swin_attn_lo(
    const float* __restrict__ x, const bf16* __restrict__ wqf,
    const float* __restrict__ wqkv_b, const float* __restrict__ bias_table,
    bf16* __restrict__ yb) {
  __shared__ __align__(16) bf16 xs[64][264];
  __shared__ __align__(16) bf16 uni[4][2304];
  swin_attn_body(xs, uni, x, wqf, wqkv_b, bias_table, yb);
}

// K2: out[131072,256] f32 = yb(bf16) @ wp(frag-order bf16) + wp_b. Zero LDS.
__global__ __launch_bounds__(256) void proj_ws(
    const bf16* __restrict__ yb, const bf16* __restrict__ wpf,
    const float* __restrict__ wp_b, float* __restrict__ out) {
  const int tid = threadIdx.x;
  const int wave = tid >> 6, lane = tid & 63;
  const int lr = lane & 15, quad = lane >> 4;
  const size_t row0 = (size_t)blockIdx.x * 64;

  f32x4 acc[4][4] = {};
#pragma unroll
  for (int kb = 0; kb < 8; ++kb) {
    bf16x8 a[4], b[4];
#pragma unroll
    for (int mt = 0; mt < 4; ++mt)
      a[mt] = *(const bf16x8*)&yb[(row0 + mt * 16 + lr) * 256 + kb * 32 + quad * 8];
#pragma unroll
    for (int nt = 0; nt < 4; ++nt)
      b[nt] = *(const bf16x8*)&wpf[(size_t)(((wave * 4 + nt) * 8 + kb) * 64 + lane) * 8];
#pragma unroll
    for (int mt = 0; mt < 4; ++mt)
#pragma unroll
      for (int nt = 0; nt < 4; ++nt) acc[mt][nt] = MFMA16(a[mt], b[nt], acc[mt][nt]);
  }
#pragma unroll
  for (int nt = 0; nt < 4; ++nt) {
    const int col = (wave * 4 + nt) * 16 + lr;
    const float bv = wp_b[col];
#pragma unroll
    for (int mt = 0; mt < 4; ++mt)
#pragma unroll
      for (int r = 0; r < 4; ++r)
        out[(row0 + mt * 16 + quad * 4 + r) * 256 + col] = acc[mt][nt][r] + bv;
  }
}

// ======================= FALLBACK PATH (original verified kernels) =======================

#define QS_OFF 0
#define KS_OFF 2304
#define VT_OFF 4608
#define PL_OFF 0
#define UNI_SZ 6784

__global__ __launch_bounds__(256) void fused_qkv_attn(
    const float* __restrict__ x, const float* __restrict__ wqkv_w,
    const float* __restrict__ wqkv_b, const float* __restrict__ bias_table,
    float* __restrict__ out) {
  __shared__ bf16 xs[64][72];
  __shared__ bf16 uni[4][UNI_SZ];

  const int tid = threadIdx.x;
  const int wave = tid >> 6, lane = tid & 63;
  const int lr = lane & 15, quad = lane >> 4;
  const int win = blockIdx.x;
  const int batch = win >> 10, wy = (win >> 5) & 31, wx = win & 31;
  const int base = batch * 65536 + wy * 2048 + wx * 8;
  bf16* const U = &uni[wave][0];

  const f32x4 zero = {0.f, 0.f, 0.f, 0.f};
  const float scale = 0.17677669529663687f;

  for (int rep = 0; rep < 2; rep++) {
    const int h = wave * 2 + rep;
    const int cb[6] = {h * 32,       h * 32 + 16,
                       256 + h * 32, 256 + h * 32 + 16,
                       512 + h * 32, 512 + h * 32 + 16};

    f32x4 acc[4][6] = {};
    for (int kc = 0; kc < 4; kc++) {
      __syncthreads();
      {
        const int t = tid >> 2, c0 = (tid & 3) * 16;
        const float* xp = x + (size_t)(base + (t >> 3) * 256 + (t & 7)) * 256 + kc * 64 + c0;
        *(bf16x8*)&xs[t][c0] = cvt8(xp);
        *(bf16x8*)&xs[t][c0 + 8] = cvt8(xp + 8);
      }
      __syncthreads();
#pragma unroll
      for (int k2 = 0; k2 < 64; k2 += 32) {
        bf16x8 a[4], b[6];
#pragma unroll
        for (int mi = 0; mi < 4; mi++) a[mi] = lds8(&xs[mi * 16 + lr][k2 + quad * 8]);
#pragma unroll
        for (int nj = 0; nj < 6; nj++)
          b[nj] = cvt8(wqkv_w + (size_t)(cb[nj] + lr) * 256 + kc * 64 + k2 + quad * 8);
#pragma unroll
        for (int mi = 0; mi < 4; mi++)
#pragma unroll
          for (int nj = 0; nj < 6; nj++) acc[mi][nj] = MFMA16(a[mi], b[nj], acc[mi][nj]);
      }
    }

#pragma unroll
    for (int nj = 0; nj < 6; nj++) {
      const float bv = wqkv_b[cb[nj] + lr];
#pragma unroll
      for (int mi = 0; mi < 4; mi++)
#pragma unroll
        for (int r = 0; r < 4; r++) {
          const int tok = mi * 16 + quad * 4 + r;
          const float v = acc[mi][nj][r] + bv;
          if (nj < 2)      U[QS_OFF + tok * 36 + nj * 16 + lr] = (bf16)v;
          else if (nj < 4) U[KS_OFF + tok * 36 + (nj - 2) * 16 + lr] = (bf16)v;
          else             U[VT_OFF + ((nj - 4) * 16 + lr) * 68 + tok] = (bf16)v;
        }
    }

    bf16x8 qf[4], kf[4];
#pragma unroll
    for (int i = 0; i < 4; i++) {
      qf[i] = lds8(&U[QS_OFF + (i * 16 + lr) * 36 + quad * 8]);
      kf[i] = lds8(&U[KS_OFF + (i * 16 + lr) * 36 + quad * 8]);
    }
    f32x4 s[4][4];
#pragma unroll
    for (int mi = 0; mi < 4; mi++)
#pragma unroll
      for (int nj = 0; nj < 4; nj++) s[mi][nj] = MFMA16(qf[mi], kf[nj], zero);

#pragma unroll
    for (int mi = 0; mi < 4; mi++)
#pragma unroll
      for (int nj = 0; nj < 4; nj++)
#pragma unroll
        for (int r = 0; r < 4; r++) {
          const int qt = mi * 16 + quad * 4 + r;
          const int kt = nj * 16 + lr;
          const int idx = ((qt >> 3) - (kt >> 3) + 7) * 15 + ((qt & 7) - (kt & 7) + 7);
          s[mi][nj][r] = s[mi][nj][r] * scale + bias_table[idx * 8 + h];
        }

#pragma unroll
    for (int mi = 0; mi < 4; mi++)
#pragma unroll
      for (int r = 0; r < 4; r++) {
        float mx = -1e30f;
#pragma unroll
        for (int nj = 0; nj < 4; nj++) mx = fmaxf(mx, s[mi][nj][r]);
#pragma unroll
        for (int off = 1; off < 16; off <<= 1) mx = fmaxf(mx, __shfl_xor(mx, off, 64));
        float sum = 0.f;
#pragma unroll
        for (int nj = 0; nj < 4; nj++) {
          const float e = __expf(s[mi][nj][r] - mx);
          s[mi][nj][r] = e;
          sum += e;
        }
#pragma unroll
        for (int off = 1; off < 16; off <<= 1) sum += __shfl_xor(sum, off, 64);
        const float inv = 1.0f / sum;
#pragma unroll
        for (int nj = 0; nj < 4; nj++)
          U[PL_OFF + (mi * 16 + quad * 4 + r) * 68 + nj * 16 + lr] = (bf16)(s[mi][nj][r] * inv);
      }

    f32x4 o[4][2] = {};
#pragma unroll
    for (int kq = 0; kq < 2; kq++) {
      bf16x8 pa[4], vb[2];
#pragma unroll
      for (int mi = 0; mi < 4; mi++)
        pa[mi] = lds8(&U[PL_OFF + (mi * 16 + lr) * 68 + kq * 32 + quad * 8]);
#pragma unroll
      for (int ni = 0; ni < 2; ni++)
        vb[ni] = lds8(&U[VT_OFF + (ni * 16 + lr) * 68 + kq * 32 + quad * 8]);
#pragma unroll
      for (int mi = 0; mi < 4; mi++)
#pragma unroll
        for (int ni = 0; ni < 2; ni++) o[mi][ni] = MFMA16(pa[mi], vb[ni], o[mi][ni]);
    }

#pragma unroll
    for (int mi = 0; mi < 4; mi++)
#pragma unroll
      for (int ni = 0; ni < 2; ni++)
#pragma unroll
        for (int r = 0; r < 4; r++) {
          const int t = mi * 16 + quad * 4 + r;
          const size_t row = (size_t)(base + (t >> 3) * 256 + (t & 7));
          out[row * 256 + h * 32 + ni * 16 + lr] = o[mi][ni][r];
        }
  }
}

__global__ __launch_bounds__(256) void proj_inplace(
    float* io, const float* __restrict__ W, const float* __restrict__ bias) {
  const int tid = threadIdx.x;
  const int wave = tid >> 6, lane = tid & 63;
  const int lr = lane & 15, quad = lane >> 4;
  const int row0 = blockIdx.x * 128 + (wave >> 1) * 64;
  const int col0 = (wave & 1) * 128;

  f32x4 acc[4][8] = {};
#pragma unroll
  for (int kk = 0; kk < 256; kk += 32) {
    bf16x8 a[4], b[8];
#pragma unroll
    for (int mi = 0; mi < 4; mi++)
      a[mi] = cvt8(io + (size_t)(row0 + mi * 16 + lr) * 256 + kk + quad * 8);
#pragma unroll
    for (int nj = 0; nj < 8; nj++)
      b[nj] = cvt8(W + (size_t)(col0 + nj * 16 + lr) * 256 + kk + quad * 8);
#pragma unroll
    for (int mi = 0; mi < 4; mi++)
#pragma unroll
      for (int nj = 0; nj < 8; nj++) acc[mi][nj] = MFMA16(a[mi], b[nj], acc[mi][nj]);
  }
  __syncthreads();
#pragma unroll
  for (int mi = 0; mi < 4; mi++)
#pragma unroll
    for (int nj = 0; nj < 8; nj++) {
      const int col = col0 + nj * 16 + lr;
      const float bv = bias[col];
#pragma unroll
      for (int r = 0; r < 4; r++) {
        const int row = row0 + mi * 16 + quad * 4 + r;
        io[(size_t)row * 256 + col] = acc[mi][nj][r] + bv;
      }
    }
}

extern "C" void kernel_launch(void* const* d_in, const int* in_sizes, int n_in,
                              void* d_out, int out_size, void* d_ws, size_t ws_size,
                              hipStream_t stream) {
  const float* x = (const float*)d_in[0];
  // d_in[1]=h, d_in[2]=w (fixed 256)
  const float* wqkv_w = (const float*)d_in[3];
  const float* wqkv_b = (const float*)d_in[4];
  const float* wp_w = (const float*)d_in[5];
  const float* wp_b = (const float*)d_in[6];
  const float* bias_table = (const float*)d_in[7];
  float* out = (float*)d_out;

  const size_t W_ELEMS = 196608 + 65536;                       // frag-order bf16 weights
  const size_t NEED = W_ELEMS * 2 + (size_t)131072 * 256 * 2;  // + yb = 67,633,152 B

  if (ws_size >= NEED) {
    bf16* wbf = (bf16*)d_ws;        // [0,196608) wqkv frag, [196608,262144) wp frag
    bf16* yb = wbf + W_ELEMS;       // y bf16 [131072][256]
    // Runtime spill guard: launch the (256,3) twin only if it allocated zero scratch.
    static int use_hi = -1;
    if (use_hi < 0) {
      hipFuncAttributes attr{};
      const hipError_t e =
          hipFuncGetAttributes(&attr, reinterpret_cast<const void*>(&swin_attn_hi));
      use_hi = (e == hipSuccess && attr.localSizeBytes == 0) ? 1 : 0;
    }
    cvt_weights_v3<<<128, 256, 0, stream>>>(wqkv_w, wp_w, wbf);
    if (use_hi)
      swin_attn_hi<<<4096, 256, 0, stream>>>(x, wbf, wqkv_b, bias_table, yb);
    else
      swin_attn_lo<<<4096, 256, 0, stream>>>(x, wbf, wqkv_b, bias_table, yb);
    proj_ws<<<2048, 256, 0, stream>>>(yb, wbf + 196608, wp_b, out);
  } else {
    fused_qkv_attn<<<2048, 256, 0, stream>>>(x, wqkv_w, wqkv_b, bias_table, out);
    proj_inplace<<<1024, 256, 0, stream>>>(out, wp_w, wp_b);
  }
}

// Round 8
// 428.697 us; speedup vs baseline: 1.2518x; 1.2518x over previous
//
#include <hip/hip_runtime.h>
#include <hip/hip_bf16.h>

// SpatialWindowSelfAttention — MI355X gfx950.
// v8 = v4's proven fused structure (2 heads/wave, LDS Vt, frag_xpose, y-exchange
// + out-proj in one kernel) with the staging phase DELETED:
//   K0 prep: weights -> MFMA-frag order AND x -> bf16 in fragment order
//     xbf[win][kb][tok][32] (one-time 201MB stream).
//   K1: x fragments are direct, fully-coalesced 16B global loads from xbf
//     (32KB/window, L2-resident across the 6 re-reads). No staging loop, no
//     cvt VALU, ONE barrier total (y-exchange). No K2, no y round-trip.
// R7 evidence: occupancy-pushing is a dead end (v4/v6/v7 all ~305us; halved
// per-wave work = exactly halved block wall, same throughput). This round cuts
// per-wave instruction fat + serialization instead.
// hi (256,3) twin behind the spill guard (R2/R5/R6 lesson), lo = plain bounds.
// Fallback path (ws too small): original verified two-kernel version.

typedef __bf16 bf16;
typedef bf16 bf16x2 __attribute__((ext_vector_type(2)));
typedef bf16 bf16x4 __attribute__((ext_vector_type(4)));
typedef bf16 bf16x8 __attribute__((ext_vector_type(8)));
typedef float f32x4 __attribute__((ext_vector_type(4)));
typedef int i32x4 __attribute__((ext_vector_type(4)));

#define MFMA16(a, b, c) __builtin_amdgcn_mfma_f32_16x16x32_bf16(a, b, c, 0, 0, 0)

__device__ __forceinline__ bf16x8 cvt8(const float* p) {  // 32B-aligned f32 -> bf16x8
  f32x4 lo = *(const f32x4*)p;
  f32x4 hi = *(const f32x4*)(p + 4);
  bf16x8 r;
#pragma unroll
  for (int j = 0; j < 4; j++) { r[j] = (bf16)lo[j]; r[j + 4] = (bf16)hi[j]; }
  return r;
}
__device__ __forceinline__ bf16x8 lds8(const bf16* p) {  // 8B-aligned LDS pair
  bf16x4 lo = *(const bf16x4*)p;
  bf16x4 hi = *(const bf16x4*)(p + 4);
  return __builtin_shufflevector(lo, hi, 0, 1, 2, 3, 4, 5, 6, 7);
}
__device__ __forceinline__ int pack2(float a, float b) {  // 2 f32 -> bf16x2 dword
  bf16x2 t; t[0] = (bf16)a; t[1] = (bf16)b;
  return __builtin_bit_cast(int, t);
}

// C-layout -> A/B-frag transform (verified v3..v7).
__device__ __forceinline__ bf16x8 frag_xpose(int aLo, int bLo, int aHi, int bHi,
                                             int L0, int L1, bool hiq) {
  const int a0 = __shfl(aLo, L0, 64), a1 = __shfl(aHi, L0, 64);
  const int b0 = __shfl(bLo, L0, 64), b1 = __shfl(bHi, L0, 64);
  const int a0h = __shfl(aLo, L1, 64), a1h = __shfl(aHi, L1, 64);
  const int b0h = __shfl(bLo, L1, 64), b1h = __shfl(bHi, L1, 64);
  const i32x4 w = {hiq ? a1 : a0, hiq ? b1 : b0, hiq ? a1h : a0h, hiq ? b1h : b0h};
  return __builtin_bit_cast(bf16x8, w);
}

// ======================= FAST PATH (v8) =======================

// K0: blocks [0,128): weights -> frag order (verified cvt_weights_v3 logic).
//     blocks [128,2176): x -> bf16 fragment order xbf[win][kb][tok][32].
__global__ __launch_bounds__(256) void prep_v8(
    const float* __restrict__ wq, const float* __restrict__ wp,
    const float* __restrict__ x, bf16* __restrict__ wbf, bf16* __restrict__ xbf) {
  const int bid = blockIdx.x;
  if (bid < 128) {
    const int did = bid * 256 + threadIdx.x;  // [0, 32768)
    const float* src;
    bf16* o;
    if (did < 24576) {
      const int ct = did >> 9, rem = did & 511, kb = rem >> 6, ln = rem & 63;
      src = wq + (size_t)(ct * 16 + (ln & 15)) * 256 + kb * 32 + (ln >> 4) * 8;
      o = wbf + (size_t)did * 8;
    } else {
      const int d2 = did - 24576;
      const int ct = d2 >> 9, rem = d2 & 511, kb = rem >> 6, ln = rem & 63;
      src = wp + (size_t)(ct * 16 + (ln & 15)) * 256 + kb * 32 + (ln >> 4) * 8;
      o = wbf + 196608 + (size_t)d2 * 8;
    }
    *(bf16x8*)o = cvt8(src);
  } else {
    const int win = bid - 128;  // [0,2048)
    const int batch = win >> 10, wy = (win >> 5) & 31, wx = win & 31;
    const int base = batch * 65536 + wy * 2048 + wx * 8;
    bf16* const xw = xbf + (size_t)win * 16384;
#pragma unroll
    for (int vv = 0; vv < 2; ++vv) {
      const int v = threadIdx.x + vv * 256;  // [0,512): (kb,tok)
      const int kb = v >> 6, tok = v & 63;
      const float* src = x + (size_t)(base + ((tok >> 3) << 8) + (tok & 7)) * 256 + kb * 32;
      bf16* dst = xw + v * 32;
#pragma unroll
      for (int g = 0; g < 4; ++g) *(bf16x8*)(dst + g * 8) = cvt8(src + g * 8);
    }
  }
}

// One 2-tile projection pass over K=256 (v6-verified math, x from global xb).
__device__ __forceinline__ void proj2_frags_g(
    const int ct0, const int cb0, const int lane, const int lr, const int quad,
    const bf16* __restrict__ xb, const bf16* __restrict__ wqf,
    const float* __restrict__ wqkv_b, const int L0, const int L1, const bool hiq,
    bf16x8* __restrict__ fr) {
  f32x4 acc[2][4] = {};
#pragma unroll
  for (int kb = 0; kb < 8; ++kb) {
    bf16x8 b[4];
#pragma unroll
    for (int nj = 0; nj < 4; ++nj)
      b[nj] = *(const bf16x8*)&xb[kb * 2048 + (nj * 16 + lr) * 32 + quad * 8];
#pragma unroll
    for (int mi = 0; mi < 2; ++mi) {
      const bf16x8 a = *(const bf16x8*)&wqf[(size_t)(((ct0 + mi) * 8 + kb) * 64 + lane) * 8];
#pragma unroll
      for (int nj = 0; nj < 4; ++nj) acc[mi][nj] = MFMA16(a, b[nj], acc[mi][nj]);
    }
  }
#pragma unroll
  for (int mi = 0; mi < 2; ++mi) {
    const f32x4 bb = *(const f32x4*)&wqkv_b[cb0 + mi * 16 + quad * 4];
#pragma unroll
    for (int nj = 0; nj < 4; ++nj)
#pragma unroll
      for (int r = 0; r < 4; ++r) acc[mi][nj][r] += bb[r];
  }
#pragma unroll
  for (int t = 0; t < 4; ++t)
    fr[t] = frag_xpose(pack2(acc[0][t][0], acc[0][t][1]), pack2(acc[0][t][2], acc[0][t][3]),
                       pack2(acc[1][t][0], acc[1][t][1]), pack2(acc[1][t][2], acc[1][t][3]),
                       L0, L1, hiq);
}

// Per-head attention (v6-verified math; x from xbf). y packed into ob[16].
__device__ __forceinline__ void attn_head_v8(
    const int h, const int lane, const int lr, const int quad,
    const bf16* __restrict__ xb, bf16* __restrict__ U,
    const bf16* __restrict__ wqf, const float* __restrict__ wqkv_b,
    const float* __restrict__ bias_table, int* __restrict__ ob) {
  const f32x4 zero = {0.f, 0.f, 0.f, 0.f};
  const float scale = 0.17677669529663687f;  // 1/sqrt(32)
  const int L0 = ((quad & 1) << 5) | lr, L1 = L0 + 16;
  const bool hiq = quad >= 2;

  bf16x8 qf[4], kf[4];
  proj2_frags_g(2 * h, h * 32, lane, lr, quad, xb, wqf, wqkv_b, L0, L1, hiq, qf);
  proj2_frags_g(16 + 2 * h, 256 + h * 32, lane, lr, quad, xb, wqf, wqkv_b, L0, L1, hiq, kf);

  bf16x8 pa[4][2];
#pragma unroll
  for (int qp = 0; qp < 2; ++qp) {
    f32x4 s2[4][2];
#pragma unroll
    for (int kt = 0; kt < 4; ++kt)
#pragma unroll
      for (int j = 0; j < 2; ++j) s2[kt][j] = MFMA16(kf[kt], qf[2 * qp + j], zero);
#pragma unroll
    for (int j = 0; j < 2; ++j) {
      const int qt = 2 * qp + j;
      const int qtok = qt * 16 + lr;
#pragma unroll
      for (int kt = 0; kt < 4; ++kt)
#pragma unroll
        for (int r = 0; r < 4; ++r) {
          const int ktok = kt * 16 + quad * 4 + r;
          const int idx = ((qtok >> 3) - (ktok >> 3) + 7) * 15 + (qtok & 7) - (ktok & 7) + 7;
          s2[kt][j][r] = s2[kt][j][r] * scale + bias_table[idx * 8 + h];
        }
      float mx = -1e30f;
#pragma unroll
      for (int kt = 0; kt < 4; ++kt)
#pragma unroll
        for (int r = 0; r < 4; ++r) mx = fmaxf(mx, s2[kt][j][r]);
      mx = fmaxf(mx, __shfl_xor(mx, 16, 64));
      mx = fmaxf(mx, __shfl_xor(mx, 32, 64));
      float sum = 0.f;
#pragma unroll
      for (int kt = 0; kt < 4; ++kt)
#pragma unroll
        for (int r = 0; r < 4; ++r) {
          const float e = __expf(s2[kt][j][r] - mx);
          s2[kt][j][r] = e;
          sum += e;
        }
      sum += __shfl_xor(sum, 16, 64);
      sum += __shfl_xor(sum, 32, 64);
      const float inv = 1.0f / sum;
#pragma unroll
      for (int kq = 0; kq < 2; ++kq)
        pa[qt][kq] = frag_xpose(
            pack2(s2[2 * kq][j][0] * inv, s2[2 * kq][j][1] * inv),
            pack2(s2[2 * kq][j][2] * inv, s2[2 * kq][j][3] * inv),
            pack2(s2[2 * kq + 1][j][0] * inv, s2[2 * kq + 1][j][1] * inv),
            pack2(s2[2 * kq + 1][j][2] * inv, s2[2 * kq + 1][j][3] * inv),
            L0, L1, hiq);
    }
  }

  // V pass -> Vt LDS (acc freed into LDS)
  {
    f32x4 av[2][4] = {};
    const int ctv = 32 + 2 * h;
#pragma unroll
    for (int kb = 0; kb < 8; ++kb) {
      bf16x8 b[4];
#pragma unroll
      for (int nj = 0; nj < 4; ++nj)
        b[nj] = *(const bf16x8*)&xb[kb * 2048 + (nj * 16 + lr) * 32 + quad * 8];
#pragma unroll
      for (int mi = 0; mi < 2; ++mi) {
        const bf16x8 a = *(const bf16x8*)&wqf[(size_t)(((ctv + mi) * 8 + kb) * 64 + lane) * 8];
#pragma unroll
        for (int nj = 0; nj < 4; ++nj) av[mi][nj] = MFMA16(a, b[nj], av[mi][nj]);
      }
    }
#pragma unroll
    for (int mi = 0; mi < 2; ++mi) {
      const f32x4 bb = *(const f32x4*)&wqkv_b[512 + h * 32 + mi * 16 + quad * 4];
#pragma unroll
      for (int nj = 0; nj < 4; ++nj)
#pragma unroll
        for (int r = 0; r < 4; ++r)
          U[(mi * 16 + quad * 4 + r) * 72 + nj * 16 + lr] = (bf16)(av[mi][nj][r] + bb[r]);
    }
  }

  // O = P @ V
  f32x4 o[4][2] = {};
#pragma unroll
  for (int kq = 0; kq < 2; ++kq) {
    bf16x8 vb[2];
#pragma unroll
    for (int ni = 0; ni < 2; ++ni) vb[ni] = lds8(&U[(ni * 16 + lr) * 72 + kq * 32 + quad * 8]);
#pragma unroll
    for (int mt = 0; mt < 4; ++mt)
#pragma unroll
      for (int ni = 0; ni < 2; ++ni) o[mt][ni] = MFMA16(pa[mt][kq], vb[ni], o[mt][ni]);
  }
#pragma unroll
  for (int mt = 0; mt < 4; ++mt)
#pragma unroll
    for (int ni = 0; ni < 2; ++ni)
#pragma unroll
      for (int w2 = 0; w2 < 2; ++w2)
        ob[(mt * 2 + ni) * 2 + w2] = pack2(o[mt][ni][2 * w2], o[mt][ni][2 * w2 + 1]);
}

// K1 body: 2 heads/wave from xbf -> y-exchange (ONE barrier) -> out-proj.
__device__ __forceinline__ void swin_v8_body(
    bf16 (*__restrict__ ybuf)[264], bf16 (*__restrict__ uni)[2304],
    const bf16* __restrict__ xbf, const bf16* __restrict__ wqf,
    const float* __restrict__ wqkv_b, const float* __restrict__ bias_table,
    const bf16* __restrict__ wpf, const float* __restrict__ wp_b,
    float* __restrict__ out) {
  const int tid = threadIdx.x;
  const int wave = tid >> 6, lane = tid & 63;
  const int lr = lane & 15, quad = lane >> 4;
  const int win = blockIdx.x;  // [0,2048)
  const int batch = win >> 10, wy = (win >> 5) & 31, wx = win & 31;
  const int base = batch * 65536 + wy * 2048 + wx * 8;
  const bf16* const xb = xbf + (size_t)win * 16384;
  bf16* const U = &uni[wave][0];

  int ob0[16], ob1[16];
  attn_head_v8(wave * 2 + 0, lane, lr, quad, xb, U, wqf, wqkv_b, bias_table, ob0);
  attn_head_v8(wave * 2 + 1, lane, lr, quad, xb, U, wqf, wqkv_b, bias_table, ob1);

  // write y (bf16) into ybuf[tok][ch]; wave covers its 2 heads' 64 channels
#pragma unroll
  for (int rep = 0; rep < 2; ++rep) {
    const int* ob = rep ? ob1 : ob0;
    const int hh = wave * 2 + rep;
#pragma unroll
    for (int mt = 0; mt < 4; ++mt)
#pragma unroll
      for (int ni = 0; ni < 2; ++ni)
#pragma unroll
        for (int w2 = 0; w2 < 2; ++w2) {
          const bf16x2 t = __builtin_bit_cast(bf16x2, ob[(mt * 2 + ni) * 2 + w2]);
#pragma unroll
          for (int e = 0; e < 2; ++e)
            ybuf[mt * 16 + quad * 4 + w2 * 2 + e][hh * 32 + ni * 16 + lr] = t[e];
        }
  }
  __syncthreads();  // THE barrier: y complete
  // out = y @ wp^T + b; wave owns 64 cols
  f32x4 ap[4][4] = {};
#pragma unroll
  for (int kb = 0; kb < 8; ++kb) {
    bf16x8 a[4], b[4];
#pragma unroll
    for (int mt = 0; mt < 4; ++mt) a[mt] = lds8(&ybuf[mt * 16 + lr][kb * 32 + quad * 8]);
#pragma unroll
    for (int nt = 0; nt < 4; ++nt)
      b[nt] = *(const bf16x8*)&wpf[(size_t)(((wave * 4 + nt) * 8 + kb) * 64 + lane) * 8];
#pragma unroll
    for (int mt = 0; mt < 4; ++mt)
#pragma unroll
      for (int nt = 0; nt < 4; ++nt) ap[mt][nt] = MFMA16(a[mt], b[nt], ap[mt][nt]);
  }
#pragma unroll
  for (int nt = 0; nt < 4; ++nt) {
    const int col = (wave * 4 + nt) * 16 + lr;
    const float bv = wp_b[col];
#pragma unroll
    for (int mt = 0; mt < 4; ++mt)
#pragma unroll
      for (int r = 0; r < 4; ++r) {
        const int t = mt * 16 + quad * 4 + r;
        const size_t grow = (size_t)(base + ((t >> 3) << 8) + (t & 7));
        out[grow * 256 + col] = ap[mt][nt][r] + bv;
      }
  }
}

__global__ __launch_bounds__(256, 3) void swin_v8_hi(
    const bf16* __restrict__ xbf, const bf16* __restrict__ wqf,
    const float* __restrict__ wqkv_b, const float* __restrict__ bias_table,
    const bf16* __restrict__ wpf, const float* __restrict__ wp_b,
    float* __restrict__ out) {
  __shared__ __align__(16) bf16 ybuf[64][264];
  __shared__ __align__(16) bf16 uni[4][2304];
  swin_v8_body(ybuf, uni, xbf, wqf, wqkv_b, bias_table, wpf, wp_b, out);
}

__global__ __launch_bounds__(256) void swin_v8_lo(
    const bf16* __restrict__ xbf, const bf16* __restrict__ wqf,
    const float* __restrict__ wqkv_b, const float* __restrict__ bias_table,
    const bf16* __restrict__ wpf, const float* __restrict__ wp_b,
    float* __restrict__ out) {
  __shared__ __align__(16) bf16 ybuf[64][264];
  __shared__ __align__(16) bf16 uni[4][2304];
  swin_v8_body(ybuf, uni, xbf, wqf, wqkv_b, bias_table, wpf, wp_b, out);
}

// ======================= FALLBACK PATH (original verified kernels) =======================

#define QS_OFF 0
#define KS_OFF 2304
#define VT_OFF 4608
#define PL_OFF 0
#define UNI_SZ 6784

__global__ __launch_bounds__(256) void fused_qkv_attn(
    const float* __restrict__ x, const float* __restrict__ wqkv_w,
    const float* __restrict__ wqkv_b, const float* __restrict__ bias_table,
    float* __restrict__ out) {
  __shared__ bf16 xs[64][72];
  __shared__ bf16 uni[4][UNI_SZ];

  const int tid = threadIdx.x;
  const int wave = tid >> 6, lane = tid & 63;
  const int lr = lane & 15, quad = lane >> 4;
  const int win = blockIdx.x;
  const int batch = win >> 10, wy = (win >> 5) & 31, wx = win & 31;
  const int base = batch * 65536 + wy * 2048 + wx * 8;
  bf16* const U = &uni[wave][0];

  const f32x4 zero = {0.f, 0.f, 0.f, 0.f};
  const float scale = 0.17677669529663687f;

  for (int rep = 0; rep < 2; rep++) {
    const int h = wave * 2 + rep;
    const int cb[6] = {h * 32,       h * 32 + 16,
                       256 + h * 32, 256 + h * 32 + 16,
                       512 + h * 32, 512 + h * 32 + 16};

    f32x4 acc[4][6] = {};
    for (int kc = 0; kc < 4; kc++) {
      __syncthreads();
      {
        const int t = tid >> 2, c0 = (tid & 3) * 16;
        const float* xp = x + (size_t)(base + (t >> 3) * 256 + (t & 7)) * 256 + kc * 64 + c0;
        *(bf16x8*)&xs[t][c0] = cvt8(xp);
        *(bf16x8*)&xs[t][c0 + 8] = cvt8(xp + 8);
      }
      __syncthreads();
#pragma unroll
      for (int k2 = 0; k2 < 64; k2 += 32) {
        bf16x8 a[4], b[6];
#pragma unroll
        for (int mi = 0; mi < 4; mi++) a[mi] = lds8(&xs[mi * 16 + lr][k2 + quad * 8]);
#pragma unroll
        for (int nj = 0; nj < 6; nj++)
          b[nj] = cvt8(wqkv_w + (size_t)(cb[nj] + lr) * 256 + kc * 64 + k2 + quad * 8);
#pragma unroll
        for (int mi = 0; mi < 4; mi++)
#pragma unroll
          for (int nj = 0; nj < 6; nj++) acc[mi][nj] = MFMA16(a[mi], b[nj], acc[mi][nj]);
      }
    }

#pragma unroll
    for (int nj = 0; nj < 6; nj++) {
      const float bv = wqkv_b[cb[nj] + lr];
#pragma unroll
      for (int mi = 0; mi < 4; mi++)
#pragma unroll
        for (int r = 0; r < 4; r++) {
          const int tok = mi * 16 + quad * 4 + r;
          const float v = acc[mi][nj][r] + bv;
          if (nj < 2)      U[QS_OFF + tok * 36 + nj * 16 + lr] = (bf16)v;
          else if (nj < 4) U[KS_OFF + tok * 36 + (nj - 2) * 16 + lr] = (bf16)v;
          else             U[VT_OFF + ((nj - 4) * 16 + lr) * 68 + tok] = (bf16)v;
        }
    }

    bf16x8 qf[4], kf[4];
#pragma unroll
    for (int i = 0; i < 4; i++) {
      qf[i] = lds8(&U[QS_OFF + (i * 16 + lr) * 36 + quad * 8]);
      kf[i] = lds8(&U[KS_OFF + (i * 16 + lr) * 36 + quad * 8]);
    }
    f32x4 s[4][4];
#pragma unroll
    for (int mi = 0; mi < 4; mi++)
#pragma unroll
      for (int nj = 0; nj < 4; nj++) s[mi][nj] = MFMA16(qf[mi], kf[nj], zero);

#pragma unroll
    for (int mi = 0; mi < 4; mi++)
#pragma unroll
      for (int nj = 0; nj < 4; nj++)
#pragma unroll
        for (int r = 0; r < 4; r++) {
          const int qt = mi * 16 + quad * 4 + r;
          const int kt = nj * 16 + lr;
          const int idx = ((qt >> 3) - (kt >> 3) + 7) * 15 + ((qt & 7) - (kt & 7) + 7);
          s[mi][nj][r] = s[mi][nj][r] * scale + bias_table[idx * 8 + h];
        }

#pragma unroll
    for (int mi = 0; mi < 4; mi++)
#pragma unroll
      for (int r = 0; r < 4; r++) {
        float mx = -1e30f;
#pragma unroll
        for (int nj = 0; nj < 4; nj++) mx = fmaxf(mx, s[mi][nj][r]);
#pragma unroll
        for (int off = 1; off < 16; off <<= 1) mx = fmaxf(mx, __shfl_xor(mx, off, 64));
        float sum = 0.f;
#pragma unroll
        for (int nj = 0; nj < 4; nj++) {
          const float e = __expf(s[mi][nj][r] - mx);
          s[mi][nj][r] = e;
          sum += e;
        }
#pragma unroll
        for (int off = 1; off < 16; off <<= 1) sum += __shfl_xor(sum, off, 64);
        const float inv = 1.0f / sum;
#pragma unroll
        for (int nj = 0; nj < 4; nj++)
          U[PL_OFF + (mi * 16 + quad * 4 + r) * 68 + nj * 16 + lr] = (bf16)(s[mi][nj][r] * inv);
      }

    f32x4 o[4][2] = {};
#pragma unroll
    for (int kq = 0; kq < 2; kq++) {
      bf16x8 pa[4], vb[2];
#pragma unroll
      for (int mi = 0; mi < 4; mi++)
        pa[mi] = lds8(&U[PL_OFF + (mi * 16 + lr) * 68 + kq * 32 + quad * 8]);
#pragma unroll
      for (int ni = 0; ni < 2; ni++)
        vb[ni] = lds8(&U[VT_OFF + (ni * 16 + lr) * 68 + kq * 32 + quad * 8]);
#pragma unroll
      for (int mi = 0; mi < 4; mi++)
#pragma unroll
        for (int ni = 0; ni < 2; ni++) o[mi][ni] = MFMA16(pa[mi], vb[ni], o[mi][ni]);
    }

#pragma unroll
    for (int mi = 0; mi < 4; mi++)
#pragma unroll
      for (int ni = 0; ni < 2; ni++)
#pragma unroll
        for (int r = 0; r < 4; r++) {
          const int t = mi * 16 + quad * 4 + r;
          const size_t row = (size_t)(base + (t >> 3) * 256 + (t & 7));
          out[row * 256 + h * 32 + ni * 16 + lr] = o[mi][ni][r];
        }
  }
}

__global__ __launch_bounds__(256) void proj_inplace(
    float* io, const float* __restrict__ W, const float* __restrict__ bias) {
  const int tid = threadIdx.x;
  const int wave = tid >> 6, lane = tid & 63;
  const int lr = lane & 15, quad = lane >> 4;
  const int row0 = blockIdx.x * 128 + (wave >> 1) * 64;
  const int col0 = (wave & 1) * 128;

  f32x4 acc[4][8] = {};
#pragma unroll
  for (int kk = 0; kk < 256; kk += 32) {
    bf16x8 a[4], b[8];
#pragma unroll
    for (int mi = 0; mi < 4; mi++)
      a[mi] = cvt8(io + (size_t)(row0 + mi * 16 + lr) * 256 + kk + quad * 8);
#pragma unroll
    for (int nj = 0; nj < 8; nj++)
      b[nj] = cvt8(W + (size_t)(col0 + nj * 16 + lr) * 256 + kk + quad * 8);
#pragma unroll
    for (int mi = 0; mi < 4; mi++)
#pragma unroll
      for (int nj = 0; nj < 8; nj++) acc[mi][nj] = MFMA16(a[mi], b[nj], acc[mi][nj]);
  }
  __syncthreads();
#pragma unroll
  for (int mi = 0; mi < 4; mi++)
#pragma unroll
    for (int nj = 0; nj < 8; nj++) {
      const int col = col0 + nj * 16 + lr;
      const float bv = bias[col];
#pragma unroll
      for (int r = 0; r < 4; r++) {
        const int row = row0 + mi * 16 + quad * 4 + r;
        io[(size_t)row * 256 + col] = acc[mi][nj][r] + bv;
      }
    }
}

extern "C" void kernel_launch(void* const* d_in, const int* in_sizes, int n_in,
                              void* d_out, int out_size, void* d_ws, size_t ws_size,
                              hipStream_t stream) {
  const float* x = (const float*)d_in[0];
  // d_in[1]=h, d_in[2]=w (fixed 256)
  const float* wqkv_w = (const float*)d_in[3];
  const float* wqkv_b = (const float*)d_in[4];
  const float* wp_w = (const float*)d_in[5];
  const float* wp_b = (const float*)d_in[6];
  const float* bias_table = (const float*)d_in[7];
  float* out = (float*)d_out;

  const size_t W_ELEMS = 196608 + 65536;                   // frag-order bf16 weights
  const size_t X_ELEMS = (size_t)2048 * 16384;             // xbf fragment-order
  const size_t NEED = (W_ELEMS + X_ELEMS) * 2;             // 67,633,152 B

  if (ws_size >= NEED) {
    bf16* wbf = (bf16*)d_ws;       // [0,196608) wqkv frag, [196608,262144) wp frag
    bf16* xbf = wbf + W_ELEMS;     // x bf16 fragment order [2048][8][64][32]
    // Runtime spill guard: launch the (256,3) twin only if it allocated zero scratch.
    static int use_hi = -1;
    if (use_hi < 0) {
      hipFuncAttributes attr{};
      const hipError_t e =
          hipFuncGetAttributes(&attr, reinterpret_cast<const void*>(&swin_v8_hi));
      use_hi = (e == hipSuccess && attr.localSizeBytes == 0) ? 1 : 0;
    }
    prep_v8<<<2176, 256, 0, stream>>>(wqkv_w, wp_w, x, wbf, xbf);
    if (use_hi)
      swin_v8_hi<<<2048, 256, 0, stream>>>(xbf, wbf, wqkv_b, bias_table,
                                           wbf + 196608, wp_b, out);
    else
      swin_v8_lo<<<2048, 256, 0, stream>>>(xbf, wbf, wqkv_b, bias_table,
                                           wbf + 196608, wp_b, out);
  } else {
    fused_qkv_attn<<<2048, 256, 0, stream>>>(x, wqkv_w, wqkv_b, bias_table, out);
    proj_inplace<<<1024, 256, 0, stream>>>(out, wp_w, wp_b);
  }
}